// Round 13
// baseline (452.137 us; speedup 1.0000x reference)
//
#include <hip/hip_runtime.h>
#include <hip/hip_fp16.h>
#include <math.h>

#define HEADS 8
#define HC 256
#define SLOPE 0.2f
#define SM_EPS 1e-16f
#define LDA 40           // padded k-stride (elements) for LDS tiles

typedef __attribute__((ext_vector_type(4))) _Float16 half4v;
typedef __attribute__((ext_vector_type(8))) _Float16 half8;
typedef __attribute__((ext_vector_type(4))) float f32x4;

// ---------------- CSR build: hist emits per-edge rank, fill is atomic-free -----
__global__ void hist_kernel(const int* __restrict__ dst, int* __restrict__ cnt,
                            int* __restrict__ rank, int E) {
  int e = blockIdx.x * blockDim.x + threadIdx.x;
  if (e < E) rank[e] = atomicAdd(&cnt[dst[e]], 1);
}

__global__ void scan_blocks(const int* __restrict__ cnt, int* __restrict__ excl,
                            int* __restrict__ bsums, int N) {
  __shared__ int wsum[16];
  int t = threadIdx.x;
  int i = blockIdx.x * 1024 + t;
  int v = (i < N) ? cnt[i] : 0;
  int lane = t & 63, w = t >> 6;
  int s = v;
  #pragma unroll
  for (int off = 1; off < 64; off <<= 1) {
    int u = __shfl_up(s, off);
    if (lane >= off) s += u;
  }
  if (lane == 63) wsum[w] = s;
  __syncthreads();
  if (w == 0) {
    int ws = (lane < 16) ? wsum[lane] : 0;
    #pragma unroll
    for (int off = 1; off < 16; off <<= 1) {
      int u = __shfl_up(ws, off);
      if (lane >= off) ws += u;
    }
    if (lane < 16) wsum[lane] = ws;
  }
  __syncthreads();
  int wo = (w == 0) ? 0 : wsum[w - 1];
  int incl = s + wo;
  if (i < N) excl[i] = incl - v;
  if (t == 1023) bsums[blockIdx.x] = incl;
}

__global__ void scan_sums(int* __restrict__ bsums, int nb) {
  int lane = threadIdx.x;   // 64
  int carry = 0;
  for (int c0 = 0; c0 < nb; c0 += 64) {
    int idx = c0 + lane;
    int v = (idx < nb) ? bsums[idx] : 0;
    int s = v;
    #pragma unroll
    for (int off = 1; off < 64; off <<= 1) {
      int u = __shfl_up(s, off);
      if (lane >= off) s += u;
    }
    if (idx < nb) bsums[idx] = carry + s - v;
    carry += __shfl(s, 63);
  }
}

__global__ void scan_apply(const int* __restrict__ bsums, int* __restrict__ row_ptr,
                           int N, int E) {
  int i = blockIdx.x * blockDim.x + threadIdx.x;
  if (i < N) row_ptr[i] += bsums[i >> 10];
  if (i == 0) row_ptr[N] = E;
}

// scatter edges into dst-sorted packed payload {src, ea_bits}; one 8B store
__global__ void fill_kernel(const int* __restrict__ src, const int* __restrict__ dst,
                            const float* __restrict__ ea, const int* __restrict__ row_ptr,
                            const int* __restrict__ rank, int2* __restrict__ srcea, int E) {
  int e = blockIdx.x * blockDim.x + threadIdx.x;
  if (e < E) {
    int pos = row_ptr[dst[e]] + rank[e];
    srcea[pos] = make_int2(src[e], __float_as_int(ea[e]));
  }
}

// ---- fused prep: blocks 0-255 transpose W2, 256-511 transpose W3, 512-514 wek --
__global__ void prep_kernel(const float* __restrict__ W2, __half* __restrict__ WT2,
                            const float* __restrict__ W3, __half* __restrict__ WT3,
                            const float* __restrict__ We1, const float* __restrict__ ae1,
                            const float* __restrict__ We2, const float* __restrict__ ae2,
                            const float* __restrict__ We3, const float* __restrict__ ae3,
                            float* __restrict__ wev) {
  int b = blockIdx.x;
  int t = threadIdx.x;   // 256
  if (b < 256) {
    WT2[t * HC + b] = (__half)W2[b * HC + t];
  } else if (b < 512) {
    int k = b - 256;
    WT3[t * HC + k] = (__half)W3[k * HC + t];
  } else {
    if (t >= 64) return;
    int l = b - 512;
    const float* We = (l == 0) ? We1 : (l == 1) ? We2 : We3;
    const float* ae = (l == 0) ? ae1 : (l == 1) ? ae2 : ae3;
    float p = 0.f;
    #pragma unroll
    for (int i = 0; i < 4; i++) p += We[t * 4 + i] * ae[t * 4 + i];
    p += __shfl_xor(p, 1);
    p += __shfl_xor(p, 2);
    p += __shfl_xor(p, 4);
    if ((t & 7) == 0) wev[l * 8 + (t >> 3)] = p;
  }
}

// ---------- layer-1 prep: als/ald only (h recomputed on the fly in accum) ------
__global__ void l1_prep(const float* __restrict__ x, const float* __restrict__ W,
                        const float* __restrict__ a_s, const float* __restrict__ a_d,
                        float* __restrict__ als, float* __restrict__ ald, int M) {
  __shared__ float4 Xs[16];
  int t = threadIdx.x;           // 256
  int m0 = blockIdx.x * 16;
  if (t < 16 && (m0 + t) < M) Xs[t] = *(const float4*)(x + (size_t)(m0 + t) * 4);
  __syncthreads();
  float w0 = W[0 * HC + t], w1 = W[1 * HC + t], w2 = W[2 * HC + t], w3 = W[3 * HC + t];
  float as_ = a_s[t], ad_ = a_d[t];
  #pragma unroll
  for (int r = 0; r < 16; r++) {
    int m = m0 + r;
    if (m < M) {
      float4 a = Xs[r];
      float h = a.x * w0 + a.y * w1 + a.z * w2 + a.w * w3;
      float ps = h * as_;
      float pd = h * ad_;
      #pragma unroll
      for (int mm = 1; mm < 32; mm <<= 1) {
        ps += __shfl_xor(ps, mm);
        pd += __shfl_xor(pd, mm);
      }
      if ((t & 31) == 0) {
        als[(size_t)m * HEADS + (t >> 5)] = ps;
        ald[(size_t)m * HEADS + (t >> 5)] = pd;
      }
    }
  }
}

// ------- layers 2/3 GEMM: single-pass fp16 MFMA, 128x128 block, 32 rows/wave ---
// Wave w -> rows [m0+32w, +32) (2 row-tiles), all 128 cols (8 col-tiles).
// 10 ds_read_b128 per 16 MFMA per k-iter (vs 9/8 at 64x128): 44% less LDS/MFMA.
__global__ __launch_bounds__(256) void mfma_gemm(
    const __half* __restrict__ A, const __half* __restrict__ WT,
    const float* __restrict__ a_s, const float* __restrict__ a_d,
    __half* __restrict__ Hh, float* __restrict__ als, float* __restrict__ ald, int M) {
  __shared__ _Float16 sA[128 * LDA], sB[128 * LDA];
  int t = threadIdx.x;
  int bm = blockIdx.x >> 1, bn = blockIdx.x & 1;
  int m0 = bm * 128, n0 = bn * 128;
  int wave = t >> 6, lane = t & 63, quad = lane >> 4, l16 = lane & 15;
  int sr = t >> 2;           // 0..63 (stage rows sr and sr+64)
  int sk = (t & 3) * 8;      // {0,8,16,24}

  f32x4 acc[2][8];
  #pragma unroll
  for (int s = 0; s < 2; s++)
    #pragma unroll
    for (int c = 0; c < 8; c++) acc[s][c] = (f32x4){0.f, 0.f, 0.f, 0.f};

  size_t ar0 = (size_t)min(m0 + sr, M - 1) * HC;
  size_t ar1 = (size_t)min(m0 + sr + 64, M - 1) * HC;
  size_t br0 = (size_t)(n0 + sr) * HC;
  size_t br1 = (size_t)(n0 + sr + 64) * HC;

  half8 pA0 = *(const half8*)(A + ar0 + sk);
  half8 pA1 = *(const half8*)(A + ar1 + sk);
  half8 pB0 = *(const half8*)(WT + br0 + sk);
  half8 pB1 = *(const half8*)(WT + br1 + sk);

  for (int k0 = 0; k0 < HC; k0 += 32) {
    __syncthreads();
    *(half8*)(sA + sr * LDA + sk) = pA0;
    *(half8*)(sA + (sr + 64) * LDA + sk) = pA1;
    *(half8*)(sB + sr * LDA + sk) = pB0;
    *(half8*)(sB + (sr + 64) * LDA + sk) = pB1;
    __syncthreads();
    int kn = k0 + 32;
    if (kn < HC) {
      pA0 = *(const half8*)(A + ar0 + kn + sk);
      pA1 = *(const half8*)(A + ar1 + kn + sk);
      pB0 = *(const half8*)(WT + br0 + kn + sk);
      pB1 = *(const half8*)(WT + br1 + kn + sk);
    }
    half8 av[2];
    #pragma unroll
    for (int s = 0; s < 2; s++)
      av[s] = *(const half8*)(sA + (wave * 32 + s * 16 + l16) * LDA + quad * 8);
    #pragma unroll
    for (int c = 0; c < 8; c++) {
      half8 bv = *(const half8*)(sB + (c * 16 + l16) * LDA + quad * 8);
      #pragma unroll
      for (int s = 0; s < 2; s++)
        acc[s][c] = __builtin_amdgcn_mfma_f32_16x16x32_f16(av[s], bv, acc[s][c], 0, 0, 0);
    }
  }

  float asv[8], adv[8];
  #pragma unroll
  for (int c = 0; c < 8; c++) {
    int col = n0 + c * 16 + l16;
    asv[c] = a_s[col];
    adv[c] = a_d[col];
  }
  #pragma unroll
  for (int s = 0; s < 2; s++) {
    #pragma unroll
    for (int reg = 0; reg < 4; reg++) {
      int m = m0 + wave * 32 + s * 16 + quad * 4 + reg;
      bool ok = (m < M);
      if (ok) {
        #pragma unroll
        for (int c = 0; c < 8; c++)
          Hh[(size_t)m * HC + n0 + c * 16 + l16] = (__half)acc[s][c][reg];
      }
      #pragma unroll
      for (int d = 0; d < 4; d++) {
        float ps = acc[s][2 * d][reg] * asv[2 * d] + acc[s][2 * d + 1][reg] * asv[2 * d + 1];
        float pd = acc[s][2 * d][reg] * adv[2 * d] + acc[s][2 * d + 1][reg] * adv[2 * d + 1];
        #pragma unroll
        for (int mm = 1; mm < 16; mm <<= 1) {
          ps += __shfl_xor(ps, mm);
          pd += __shfl_xor(pd, mm);
        }
        if (ok && l16 == 0) {
          als[(size_t)m * HEADS + (n0 >> 5) + d] = ps;
          ald[(size_t)m * HEADS + (n0 >> 5) + d] = pd;
        }
      }
    }
  }
}

// -------- layer-1 accum: h recomputed from x (K=4) — no h-gather at all --------
__global__ __launch_bounds__(256) void accum_l1_kernel(
    const int2* __restrict__ srcea, const int* __restrict__ row_ptr,
    const float* __restrict__ x, const float* __restrict__ W,
    const float* __restrict__ als, const float* __restrict__ ald,
    const float* __restrict__ wev, const float* __restrict__ bias,
    __half* __restrict__ Ah, int N) {
  int n = blockIdx.x * 4 + (threadIdx.x >> 6);
  if (n >= N) return;
  int lane = threadIdx.x & 63;
  int h_t = lane >> 3;
  int cbase = lane * 4;
  int base = row_ptr[n], deg = row_ptr[n + 1] - base;
  int ubase = __builtin_amdgcn_readfirstlane(base);
  int udeg = __builtin_amdgcn_readfirstlane(deg);
  float ald_h = ald[(size_t)n * HEADS + h_t];
  float we_h = wev[h_t];
  float4 wr0 = *(const float4*)(W + 0 * HC + cbase);
  float4 wr1 = *(const float4*)(W + 1 * HC + cbase);
  float4 wr2 = *(const float4*)(W + 2 * HC + cbase);
  float4 wr3 = *(const float4*)(W + 3 * HC + cbase);

  float den = 0.f;
  float4 acc = make_float4(0.f, 0.f, 0.f, 0.f);
  #pragma unroll 8
  for (int j = 0; j < udeg; j++) {
    int2 se = srcea[ubase + j];
    int s = __builtin_amdgcn_readfirstlane(se.x);
    float eav = __int_as_float(se.y);
    float l = als[(size_t)s * HEADS + h_t] + ald_h + eav * we_h;
    l = (l > 0.f) ? l : SLOPE * l;
    float p = __expf(l);
    den += p;
    float4 xv = *(const float4*)(x + (size_t)s * 4);   // uniform -> s_load
    float h0 = xv.x * wr0.x + xv.y * wr1.x + xv.z * wr2.x + xv.w * wr3.x;
    float h1 = xv.x * wr0.y + xv.y * wr1.y + xv.z * wr2.y + xv.w * wr3.y;
    float h2 = xv.x * wr0.z + xv.y * wr1.z + xv.z * wr2.z + xv.w * wr3.z;
    float h3 = xv.x * wr0.w + xv.y * wr1.w + xv.z * wr2.w + xv.w * wr3.w;
    acc.x = fmaf(p, h0, acc.x);
    acc.y = fmaf(p, h1, acc.y);
    acc.z = fmaf(p, h2, acc.z);
    acc.w = fmaf(p, h3, acc.w);
  }

  float rinv = 1.0f / (den + SM_EPS);
  float4 o;
  o.x = fmaxf(fmaf(acc.x, rinv, bias[cbase + 0]), 0.f);
  o.y = fmaxf(fmaf(acc.y, rinv, bias[cbase + 1]), 0.f);
  o.z = fmaxf(fmaf(acc.z, rinv, bias[cbase + 2]), 0.f);
  o.w = fmaxf(fmaf(acc.w, rinv, bias[cbase + 3]), 0.f);
  half4v hv;
  hv.x = (_Float16)o.x;
  hv.y = (_Float16)o.y;
  hv.z = (_Float16)o.z;
  hv.w = (_Float16)o.w;
  *(half4v*)(Ah + (size_t)n * HC + cbase) = hv;
}

// -------- layers 2/3 accum: single-pass softmax + fp16 h-gather ----------------
template <int SPLIT>
__global__ __launch_bounds__(256) void accum_kernel(
    const int2* __restrict__ srcea, const int* __restrict__ row_ptr,
    const __half* __restrict__ h, const float* __restrict__ als,
    const float* __restrict__ ald, const float* __restrict__ wev,
    const float* __restrict__ bias, float* __restrict__ out,
    __half* __restrict__ Ah, int N) {
  int n = blockIdx.x * 4 + (threadIdx.x >> 6);
  if (n >= N) return;
  int lane = threadIdx.x & 63;
  int h_t = lane >> 3;
  int base = row_ptr[n], deg = row_ptr[n + 1] - base;
  int ubase = __builtin_amdgcn_readfirstlane(base);
  int udeg = __builtin_amdgcn_readfirstlane(deg);
  float ald_h = ald[(size_t)n * HEADS + h_t];
  float we_h = wev[h_t];

  float den = 0.f, easum = 0.f;
  float4 acc = make_float4(0.f, 0.f, 0.f, 0.f);
  #pragma unroll 8
  for (int j = 0; j < udeg; j++) {
    int2 se = srcea[ubase + j];
    int s = se.x;
    float eav = __int_as_float(se.y);
    easum += eav;
    float l = als[(size_t)s * HEADS + h_t] + ald_h + eav * we_h;
    l = (l > 0.f) ? l : SLOPE * l;
    float p = __expf(l);
    den += p;
    const half4v hv = *(const half4v*)(h + (size_t)s * HC + lane * 4);
    acc.x = fmaf(p, (float)hv.x, acc.x);
    acc.y = fmaf(p, (float)hv.y, acc.y);
    acc.z = fmaf(p, (float)hv.z, acc.z);
    acc.w = fmaf(p, (float)hv.w, acc.w);
  }
  {  // self loop (layers 2/3 always)
    float mean_ea = easum / fmaxf((float)udeg, 1.0f);
    float l = als[(size_t)n * HEADS + h_t] + ald_h + mean_ea * we_h;
    l = (l > 0.f) ? l : SLOPE * l;
    float p = __expf(l);
    den += p;
    const half4v hv = *(const half4v*)(h + (size_t)n * HC + lane * 4);
    acc.x = fmaf(p, (float)hv.x, acc.x);
    acc.y = fmaf(p, (float)hv.y, acc.y);
    acc.z = fmaf(p, (float)hv.z, acc.z);
    acc.w = fmaf(p, (float)hv.w, acc.w);
  }

  float rinv = 1.0f / (den + SM_EPS);
  int cbase = lane * 4;
  float4 o;
  o.x = fmaxf(fmaf(acc.x, rinv, bias[cbase + 0]), 0.f);
  o.y = fmaxf(fmaf(acc.y, rinv, bias[cbase + 1]), 0.f);
  o.z = fmaxf(fmaf(acc.z, rinv, bias[cbase + 2]), 0.f);
  o.w = fmaxf(fmaf(acc.w, rinv, bias[cbase + 3]), 0.f);
  if (SPLIT) {
    half4v hv;
    hv.x = (_Float16)o.x;
    hv.y = (_Float16)o.y;
    hv.z = (_Float16)o.z;
    hv.w = (_Float16)o.w;
    *(half4v*)(Ah + (size_t)n * HC + cbase) = hv;
  } else {
    *(float4*)(out + (size_t)n * HC + cbase) = o;
  }
}

// ----------------------------------- driver -----------------------------------
extern "C" void kernel_launch(void* const* d_in, const int* in_sizes, int n_in,
                              void* d_out, int out_size, void* d_ws, size_t ws_size,
                              hipStream_t stream) {
  const float* x = (const float*)d_in[0];
  const int* ei = (const int*)d_in[1];
  const float* ea = (const float*)d_in[2];
  int N = in_sizes[0] / 4;   // IN = 4
  int E = in_sizes[1] / 2;
  const int* src = ei;
  const int* dst = ei + E;

  const float* W[3];
  const float* Asw[3];
  const float* Adw[3];
  const float* Wew[3];
  const float* Aew[3];
  const float* Bw[3];
  for (int l = 0; l < 3; l++) {
    W[l]   = (const float*)d_in[3 + 6 * l + 0];
    Asw[l] = (const float*)d_in[3 + 6 * l + 1];
    Adw[l] = (const float*)d_in[3 + 6 * l + 2];
    Wew[l] = (const float*)d_in[3 + 6 * l + 3];
    Aew[l] = (const float*)d_in[3 + 6 * l + 4];
    Bw[l]  = (const float*)d_in[3 + 6 * l + 5];
  }

  char* w = (char*)d_ws;
  auto alloc = [&](size_t bytes) {
    char* p = w;
    w += (bytes + 255) & ~(size_t)255;
    return p;
  };
  __half* Hh    = (__half*)alloc((size_t)N * HC * 2);   // GEMM out / gather payload
  __half* Ah    = (__half*)alloc((size_t)N * HC * 2);   // accum out / GEMM in
  int2* srcea   = (int2*)alloc((size_t)E * 8);
  int* rank     = (int*)alloc((size_t)E * 4);
  __half* WT2   = (__half*)alloc((size_t)HC * HC * 2);
  __half* WT3   = (__half*)alloc((size_t)HC * HC * 2);
  float* als    = (float*)alloc((size_t)N * HEADS * 4);
  float* ald    = (float*)alloc((size_t)N * HEADS * 4);
  float* wev    = (float*)alloc(24 * 4);
  int* cnt      = (int*)alloc((size_t)N * 4);
  int* row_ptr  = (int*)alloc(((size_t)N + 1) * 4);
  int* bsums    = (int*)alloc(((size_t)N / 1024 + 2) * 4);
  float* outf = (float*)d_out;

  int nb = (N + 1023) / 1024;
  (void)hipMemsetAsync(cnt, 0, (size_t)N * 4, stream);
  hist_kernel<<<(E + 255) / 256, 256, 0, stream>>>(dst, cnt, rank, E);
  scan_blocks<<<nb, 1024, 0, stream>>>(cnt, row_ptr, bsums, N);
  scan_sums<<<1, 64, 0, stream>>>(bsums, nb);
  scan_apply<<<(N + 255) / 256, 256, 0, stream>>>(bsums, row_ptr, N, E);
  fill_kernel<<<(E + 255) / 256, 256, 0, stream>>>(src, dst, ea, row_ptr, rank,
                                                   srcea, E);
  prep_kernel<<<515, 256, 0, stream>>>(W[1], WT2, W[2], WT3,
                                       Wew[0], Aew[0], Wew[1], Aew[1],
                                       Wew[2], Aew[2], wev);

  int agg_grid = (N + 3) / 4;
  int gemm_grid = ((N + 127) / 128) * 2;

  // ---- layer 1: als/ald prep + direct-recompute accum (no h materialization) --
  l1_prep<<<(N + 15) / 16, 256, 0, stream>>>(x, W[0], Asw[0], Adw[0], als, ald, N);
  accum_l1_kernel<<<agg_grid, 256, 0, stream>>>(srcea, row_ptr, x, W[0], als, ald,
                                                wev + 0, Bw[0], Ah, N);

  // ---- layer 2: fp16 MFMA GEMM + gather accum ----
  mfma_gemm<<<gemm_grid, 256, 0, stream>>>(Ah, WT2, Asw[1], Adw[1], Hh, als, ald, N);
  accum_kernel<1><<<agg_grid, 256, 0, stream>>>(srcea, row_ptr, Hh, als, ald,
                                                wev + 8, Bw[1], nullptr, Ah, N);

  // ---- layer 3: fp16 MFMA GEMM + gather accum, output fp32 ----
  mfma_gemm<<<gemm_grid, 256, 0, stream>>>(Ah, WT3, Asw[2], Adw[2], Hh, als, ald, N);
  accum_kernel<0><<<agg_grid, 256, 0, stream>>>(srcea, row_ptr, Hh, als, ald,
                                                wev + 16, Bw[2], outf, nullptr, N);
}

// Round 14
// 402.509 us; speedup vs baseline: 1.1233x; 1.1233x over previous
//
#include <hip/hip_runtime.h>
#include <hip/hip_fp16.h>
#include <math.h>

#define HEADS 8
#define HC 256
#define SLOPE 0.2f
#define SM_EPS 1e-16f
#define LDA 40           // padded k-stride (elements) for LDS tiles

typedef __attribute__((ext_vector_type(4))) _Float16 half4v;
typedef __attribute__((ext_vector_type(8))) _Float16 half8;
typedef __attribute__((ext_vector_type(4))) float f32x4;

// ---------------- CSR build: hist emits per-edge rank, fill is atomic-free -----
__global__ void hist_kernel(const int* __restrict__ dst, int* __restrict__ cnt,
                            int* __restrict__ rank, int E) {
  int e = blockIdx.x * blockDim.x + threadIdx.x;
  if (e < E) rank[e] = atomicAdd(&cnt[dst[e]], 1);
}

__global__ void scan_blocks(const int* __restrict__ cnt, int* __restrict__ excl,
                            int* __restrict__ bsums, int N) {
  __shared__ int wsum[16];
  int t = threadIdx.x;
  int i = blockIdx.x * 1024 + t;
  int v = (i < N) ? cnt[i] : 0;
  int lane = t & 63, w = t >> 6;
  int s = v;
  #pragma unroll
  for (int off = 1; off < 64; off <<= 1) {
    int u = __shfl_up(s, off);
    if (lane >= off) s += u;
  }
  if (lane == 63) wsum[w] = s;
  __syncthreads();
  if (w == 0) {
    int ws = (lane < 16) ? wsum[lane] : 0;
    #pragma unroll
    for (int off = 1; off < 16; off <<= 1) {
      int u = __shfl_up(ws, off);
      if (lane >= off) ws += u;
    }
    if (lane < 16) wsum[lane] = ws;
  }
  __syncthreads();
  int wo = (w == 0) ? 0 : wsum[w - 1];
  int incl = s + wo;
  if (i < N) excl[i] = incl - v;
  if (t == 1023) bsums[blockIdx.x] = incl;
}

__global__ void scan_sums(int* __restrict__ bsums, int nb) {
  int lane = threadIdx.x;   // 64
  int carry = 0;
  for (int c0 = 0; c0 < nb; c0 += 64) {
    int idx = c0 + lane;
    int v = (idx < nb) ? bsums[idx] : 0;
    int s = v;
    #pragma unroll
    for (int off = 1; off < 64; off <<= 1) {
      int u = __shfl_up(s, off);
      if (lane >= off) s += u;
    }
    if (idx < nb) bsums[idx] = carry + s - v;
    carry += __shfl(s, 63);
  }
}

__global__ void scan_apply(const int* __restrict__ bsums, int* __restrict__ row_ptr,
                           int N, int E) {
  int i = blockIdx.x * blockDim.x + threadIdx.x;
  if (i < N) row_ptr[i] += bsums[i >> 10];
  if (i == 0) row_ptr[N] = E;
}

// scatter edges into dst-sorted packed payload {src, ea_bits}; one 8B store
__global__ void fill_kernel(const int* __restrict__ src, const int* __restrict__ dst,
                            const float* __restrict__ ea, const int* __restrict__ row_ptr,
                            const int* __restrict__ rank, int2* __restrict__ srcea, int E) {
  int e = blockIdx.x * blockDim.x + threadIdx.x;
  if (e < E) {
    int pos = row_ptr[dst[e]] + rank[e];
    srcea[pos] = make_int2(src[e], __float_as_int(ea[e]));
  }
}

// ---- fused prep: blocks 0-255 WT2, 256-511 WT3, 512-514 wek, 515 l1 v_s/v_d ---
__global__ void prep_kernel(const float* __restrict__ W2, __half* __restrict__ WT2,
                            const float* __restrict__ W3, __half* __restrict__ WT3,
                            const float* __restrict__ We1, const float* __restrict__ ae1,
                            const float* __restrict__ We2, const float* __restrict__ ae2,
                            const float* __restrict__ We3, const float* __restrict__ ae3,
                            float* __restrict__ wev,
                            const float* __restrict__ W1, const float* __restrict__ as1,
                            const float* __restrict__ ad1, float* __restrict__ vsd) {
  int b = blockIdx.x;
  int t = threadIdx.x;   // 256
  if (b < 256) {
    WT2[t * HC + b] = (__half)W2[b * HC + t];
  } else if (b < 512) {
    int k = b - 256;
    WT3[t * HC + k] = (__half)W3[k * HC + t];
  } else if (b < 515) {
    if (t >= 64) return;
    int l = b - 512;
    const float* We = (l == 0) ? We1 : (l == 1) ? We2 : We3;
    const float* ae = (l == 0) ? ae1 : (l == 1) ? ae2 : ae3;
    float p = 0.f;
    #pragma unroll
    for (int i = 0; i < 4; i++) p += We[t * 4 + i] * ae[t * 4 + i];
    p += __shfl_xor(p, 1);
    p += __shfl_xor(p, 2);
    p += __shfl_xor(p, 4);
    if ((t & 7) == 0) wev[l * 8 + (t >> 3)] = p;
  } else {
    // layer-1 factored coefficients: vsd[h*4+k] = sum_c W1[k][h*32+c]*a_s[h][c]
    // (t<32: v_s), vsd[32 + h*4+k] likewise with a_d (t in 32..63)
    if (t >= 64) return;
    int which = t >> 5;          // 0 = v_s, 1 = v_d
    int idx = t & 31;
    int h = idx >> 2, k = idx & 3;
    const float* a = which ? ad1 : as1;
    float p = 0.f;
    #pragma unroll
    for (int c = 0; c < 32; c++) p += W1[k * HC + h * 32 + c] * a[h * 32 + c];
    vsd[which * 32 + idx] = p;
  }
}

// ------- layers 2/3 GEMM: single-pass fp16 MFMA, 64x128 block ------------------
__global__ __launch_bounds__(256) void mfma_gemm(
    const __half* __restrict__ A, const __half* __restrict__ WT,
    const float* __restrict__ a_s, const float* __restrict__ a_d,
    __half* __restrict__ Hh, float* __restrict__ als, float* __restrict__ ald, int M) {
  __shared__ _Float16 sA[64 * LDA], sB[128 * LDA];
  int t = threadIdx.x;
  int bm = blockIdx.x >> 1, bn = blockIdx.x & 1;
  int m0 = bm * 64, n0 = bn * 128;
  int wave = t >> 6, lane = t & 63, quad = lane >> 4, l16 = lane & 15;
  int sr = t >> 2;
  int sk = (t & 3) * 8;

  f32x4 acc[8];
  #pragma unroll
  for (int c = 0; c < 8; c++) acc[c] = (f32x4){0.f, 0.f, 0.f, 0.f};

  size_t ar = (size_t)min(m0 + sr, M - 1) * HC;
  size_t br0 = (size_t)(n0 + sr) * HC;
  size_t br1 = (size_t)(n0 + sr + 64) * HC;

  half8 pA = *(const half8*)(A + ar + sk);
  half8 pB0 = *(const half8*)(WT + br0 + sk);
  half8 pB1 = *(const half8*)(WT + br1 + sk);

  for (int k0 = 0; k0 < HC; k0 += 32) {
    __syncthreads();
    *(half8*)(sA + sr * LDA + sk) = pA;
    *(half8*)(sB + sr * LDA + sk) = pB0;
    *(half8*)(sB + (sr + 64) * LDA + sk) = pB1;
    __syncthreads();
    int kn = k0 + 32;
    if (kn < HC) {
      pA = *(const half8*)(A + ar + kn + sk);
      pB0 = *(const half8*)(WT + br0 + kn + sk);
      pB1 = *(const half8*)(WT + br1 + kn + sk);
    }
    half8 av = *(const half8*)(sA + (wave * 16 + l16) * LDA + quad * 8);
    #pragma unroll
    for (int c = 0; c < 8; c++) {
      half8 bv = *(const half8*)(sB + (c * 16 + l16) * LDA + quad * 8);
      acc[c] = __builtin_amdgcn_mfma_f32_16x16x32_f16(av, bv, acc[c], 0, 0, 0);
    }
  }

  float asv[8], adv[8];
  #pragma unroll
  for (int c = 0; c < 8; c++) {
    int col = n0 + c * 16 + l16;
    asv[c] = a_s[col];
    adv[c] = a_d[col];
  }
  #pragma unroll
  for (int reg = 0; reg < 4; reg++) {
    int m = m0 + wave * 16 + quad * 4 + reg;
    bool ok = (m < M);
    if (ok) {
      #pragma unroll
      for (int c = 0; c < 8; c++)
        Hh[(size_t)m * HC + n0 + c * 16 + l16] = (__half)acc[c][reg];
    }
    #pragma unroll
    for (int d = 0; d < 4; d++) {
      float ps = acc[2 * d][reg] * asv[2 * d] + acc[2 * d + 1][reg] * asv[2 * d + 1];
      float pd = acc[2 * d][reg] * adv[2 * d] + acc[2 * d + 1][reg] * adv[2 * d + 1];
      #pragma unroll
      for (int mm = 1; mm < 16; mm <<= 1) {
        ps += __shfl_xor(ps, mm);
        pd += __shfl_xor(pd, mm);
      }
      if (ok && l16 == 0) {
        als[(size_t)m * HEADS + (n0 >> 5) + d] = ps;
        ald[(size_t)m * HEADS + (n0 >> 5) + d] = pd;
      }
    }
  }
}

// -------- layer-1 accum: fully factored K=4 — no h, no als/ald arrays ----------
// Logit: l = x[s]·v_s[h] + x[n]·v_d[h] + ea*w_e[h]; h row rebuilt from x[s]@W1.
__global__ __launch_bounds__(256) void accum_l1_kernel(
    const int2* __restrict__ srcea, const int* __restrict__ row_ptr,
    const float* __restrict__ x, const float* __restrict__ W,
    const float* __restrict__ vsd, const float* __restrict__ wev,
    const float* __restrict__ bias, __half* __restrict__ Ah, int N) {
  int n = blockIdx.x * 4 + (threadIdx.x >> 6);
  if (n >= N) return;
  int lane = threadIdx.x & 63;
  int h_t = lane >> 3;
  int cbase = lane * 4;
  int base = row_ptr[n], deg = row_ptr[n + 1] - base;
  int ubase = __builtin_amdgcn_readfirstlane(base);
  int udeg = __builtin_amdgcn_readfirstlane(deg);
  float we_h = wev[h_t];
  float4 vs4 = *(const float4*)(vsd + h_t * 4);
  float4 vd4 = *(const float4*)(vsd + 32 + h_t * 4);
  float4 wr0 = *(const float4*)(W + 0 * HC + cbase);
  float4 wr1 = *(const float4*)(W + 1 * HC + cbase);
  float4 wr2 = *(const float4*)(W + 2 * HC + cbase);
  float4 wr3 = *(const float4*)(W + 3 * HC + cbase);
  float4 xn = *(const float4*)(x + (size_t)n * 4);
  float ald_h = xn.x * vd4.x + xn.y * vd4.y + xn.z * vd4.z + xn.w * vd4.w;

  float den = 0.f;
  float4 acc = make_float4(0.f, 0.f, 0.f, 0.f);
  #pragma unroll 8
  for (int j = 0; j < udeg; j++) {
    int2 se = srcea[ubase + j];
    int s = se.x;
    float eav = __int_as_float(se.y);
    float4 xv = *(const float4*)(x + (size_t)s * 4);   // same-addr broadcast
    float l = xv.x * vs4.x + xv.y * vs4.y + xv.z * vs4.z + xv.w * vs4.w
              + ald_h + eav * we_h;
    l = (l > 0.f) ? l : SLOPE * l;
    float p = __expf(l);
    den += p;
    float h0 = xv.x * wr0.x + xv.y * wr1.x + xv.z * wr2.x + xv.w * wr3.x;
    float h1 = xv.x * wr0.y + xv.y * wr1.y + xv.z * wr2.y + xv.w * wr3.y;
    float h2 = xv.x * wr0.z + xv.y * wr1.z + xv.z * wr2.z + xv.w * wr3.z;
    float h3 = xv.x * wr0.w + xv.y * wr1.w + xv.z * wr2.w + xv.w * wr3.w;
    acc.x = fmaf(p, h0, acc.x);
    acc.y = fmaf(p, h1, acc.y);
    acc.z = fmaf(p, h2, acc.z);
    acc.w = fmaf(p, h3, acc.w);
  }

  float rinv = 1.0f / (den + SM_EPS);
  float4 o;
  o.x = fmaxf(fmaf(acc.x, rinv, bias[cbase + 0]), 0.f);
  o.y = fmaxf(fmaf(acc.y, rinv, bias[cbase + 1]), 0.f);
  o.z = fmaxf(fmaf(acc.z, rinv, bias[cbase + 2]), 0.f);
  o.w = fmaxf(fmaf(acc.w, rinv, bias[cbase + 3]), 0.f);
  half4v hv;
  hv.x = (_Float16)o.x;
  hv.y = (_Float16)o.y;
  hv.z = (_Float16)o.z;
  hv.w = (_Float16)o.w;
  *(half4v*)(Ah + (size_t)n * HC + cbase) = hv;
}

// -------- layers 2/3 accum: single-pass softmax + fp16 h-gather ----------------
template <int SPLIT>
__global__ __launch_bounds__(256) void accum_kernel(
    const int2* __restrict__ srcea, const int* __restrict__ row_ptr,
    const __half* __restrict__ h, const float* __restrict__ als,
    const float* __restrict__ ald, const float* __restrict__ wev,
    const float* __restrict__ bias, float* __restrict__ out,
    __half* __restrict__ Ah, int N) {
  int n = blockIdx.x * 4 + (threadIdx.x >> 6);
  if (n >= N) return;
  int lane = threadIdx.x & 63;
  int h_t = lane >> 3;
  int base = row_ptr[n], deg = row_ptr[n + 1] - base;
  int ubase = __builtin_amdgcn_readfirstlane(base);
  int udeg = __builtin_amdgcn_readfirstlane(deg);
  float ald_h = ald[(size_t)n * HEADS + h_t];
  float we_h = wev[h_t];

  float den = 0.f, easum = 0.f;
  float4 acc = make_float4(0.f, 0.f, 0.f, 0.f);
  #pragma unroll 8
  for (int j = 0; j < udeg; j++) {
    int2 se = srcea[ubase + j];
    int s = se.x;
    float eav = __int_as_float(se.y);
    easum += eav;
    float l = als[(size_t)s * HEADS + h_t] + ald_h + eav * we_h;
    l = (l > 0.f) ? l : SLOPE * l;
    float p = __expf(l);
    den += p;
    const half4v hv = *(const half4v*)(h + (size_t)s * HC + lane * 4);
    acc.x = fmaf(p, (float)hv.x, acc.x);
    acc.y = fmaf(p, (float)hv.y, acc.y);
    acc.z = fmaf(p, (float)hv.z, acc.z);
    acc.w = fmaf(p, (float)hv.w, acc.w);
  }
  {  // self loop (layers 2/3 always)
    float mean_ea = easum / fmaxf((float)udeg, 1.0f);
    float l = als[(size_t)n * HEADS + h_t] + ald_h + mean_ea * we_h;
    l = (l > 0.f) ? l : SLOPE * l;
    float p = __expf(l);
    den += p;
    const half4v hv = *(const half4v*)(h + (size_t)n * HC + lane * 4);
    acc.x = fmaf(p, (float)hv.x, acc.x);
    acc.y = fmaf(p, (float)hv.y, acc.y);
    acc.z = fmaf(p, (float)hv.z, acc.z);
    acc.w = fmaf(p, (float)hv.w, acc.w);
  }

  float rinv = 1.0f / (den + SM_EPS);
  int cbase = lane * 4;
  float4 o;
  o.x = fmaxf(fmaf(acc.x, rinv, bias[cbase + 0]), 0.f);
  o.y = fmaxf(fmaf(acc.y, rinv, bias[cbase + 1]), 0.f);
  o.z = fmaxf(fmaf(acc.z, rinv, bias[cbase + 2]), 0.f);
  o.w = fmaxf(fmaf(acc.w, rinv, bias[cbase + 3]), 0.f);
  if (SPLIT) {
    half4v hv;
    hv.x = (_Float16)o.x;
    hv.y = (_Float16)o.y;
    hv.z = (_Float16)o.z;
    hv.w = (_Float16)o.w;
    *(half4v*)(Ah + (size_t)n * HC + cbase) = hv;
  } else {
    *(float4*)(out + (size_t)n * HC + cbase) = o;
  }
}

// ----------------------------------- driver -----------------------------------
extern "C" void kernel_launch(void* const* d_in, const int* in_sizes, int n_in,
                              void* d_out, int out_size, void* d_ws, size_t ws_size,
                              hipStream_t stream) {
  const float* x = (const float*)d_in[0];
  const int* ei = (const int*)d_in[1];
  const float* ea = (const float*)d_in[2];
  int N = in_sizes[0] / 4;   // IN = 4
  int E = in_sizes[1] / 2;
  const int* src = ei;
  const int* dst = ei + E;

  const float* W[3];
  const float* Asw[3];
  const float* Adw[3];
  const float* Wew[3];
  const float* Aew[3];
  const float* Bw[3];
  for (int l = 0; l < 3; l++) {
    W[l]   = (const float*)d_in[3 + 6 * l + 0];
    Asw[l] = (const float*)d_in[3 + 6 * l + 1];
    Adw[l] = (const float*)d_in[3 + 6 * l + 2];
    Wew[l] = (const float*)d_in[3 + 6 * l + 3];
    Aew[l] = (const float*)d_in[3 + 6 * l + 4];
    Bw[l]  = (const float*)d_in[3 + 6 * l + 5];
  }

  char* w = (char*)d_ws;
  auto alloc = [&](size_t bytes) {
    char* p = w;
    w += (bytes + 255) & ~(size_t)255;
    return p;
  };
  __half* Hh    = (__half*)alloc((size_t)N * HC * 2);   // GEMM out / gather payload
  __half* Ah    = (__half*)alloc((size_t)N * HC * 2);   // accum out / GEMM in
  int2* srcea   = (int2*)alloc((size_t)E * 8);
  int* rank     = (int*)alloc((size_t)E * 4);
  __half* WT2   = (__half*)alloc((size_t)HC * HC * 2);
  __half* WT3   = (__half*)alloc((size_t)HC * HC * 2);
  float* als    = (float*)alloc((size_t)N * HEADS * 4);
  float* ald    = (float*)alloc((size_t)N * HEADS * 4);
  float* wev    = (float*)alloc(24 * 4);
  float* vsd    = (float*)alloc(64 * 4);
  int* cnt      = (int*)alloc((size_t)N * 4);
  int* row_ptr  = (int*)alloc(((size_t)N + 1) * 4);
  int* bsums    = (int*)alloc(((size_t)N / 1024 + 2) * 4);
  float* outf = (float*)d_out;

  int nb = (N + 1023) / 1024;
  (void)hipMemsetAsync(cnt, 0, (size_t)N * 4, stream);
  hist_kernel<<<(E + 255) / 256, 256, 0, stream>>>(dst, cnt, rank, E);
  scan_blocks<<<nb, 1024, 0, stream>>>(cnt, row_ptr, bsums, N);
  scan_sums<<<1, 64, 0, stream>>>(bsums, nb);
  scan_apply<<<(N + 255) / 256, 256, 0, stream>>>(bsums, row_ptr, N, E);
  fill_kernel<<<(E + 255) / 256, 256, 0, stream>>>(src, dst, ea, row_ptr, rank,
                                                   srcea, E);
  prep_kernel<<<516, 256, 0, stream>>>(W[1], WT2, W[2], WT3,
                                       Wew[0], Aew[0], Wew[1], Aew[1],
                                       Wew[2], Aew[2], wev,
                                       W[0], Asw[0], Adw[0], vsd);

  int agg_grid = (N + 3) / 4;
  int gemm_grid = ((N + 63) / 64) * 2;

  // ---- layer 1: fully factored accum (no h materialization, no prep pass) ----
  accum_l1_kernel<<<agg_grid, 256, 0, stream>>>(srcea, row_ptr, x, W[0], vsd,
                                                wev + 0, Bw[0], Ah, N);

  // ---- layer 2: fp16 MFMA GEMM + gather accum ----
  mfma_gemm<<<gemm_grid, 256, 0, stream>>>(Ah, WT2, Asw[1], Adw[1], Hh, als, ald, N);
  accum_kernel<1><<<agg_grid, 256, 0, stream>>>(srcea, row_ptr, Hh, als, ald,
                                                wev + 8, Bw[1], nullptr, Ah, N);

  // ---- layer 3: fp16 MFMA GEMM + gather accum, output fp32 ----
  mfma_gemm<<<gemm_grid, 256, 0, stream>>>(Ah, WT3, Asw[2], Adw[2], Hh, als, ald, N);
  accum_kernel<0><<<agg_grid, 256, 0, stream>>>(srcea, row_ptr, Hh, als, ald,
                                                wev + 16, Bw[2], outf, nullptr, N);
}